// Round 3
// baseline (9179.303 us; speedup 1.0000x reference)
//
#include <hip/hip_runtime.h>
#include <hip/hip_bf16.h>
#include <hip/hip_fp16.h>

#define TT 2048
#define BB 16
#define DD 256
#define GG 1024   // 4U
#define UU 256

using f32x4  = __attribute__((ext_vector_type(4))) float;
using short8 = __attribute__((ext_vector_type(8))) short;
using f16x8  = __attribute__((ext_vector_type(8))) _Float16;

static __device__ __forceinline__ unsigned short f2h_u(float f){
  _Float16 h = (_Float16)f;
  return __builtin_bit_cast(unsigned short, h);
}
static __device__ __forceinline__ float h2f(unsigned short u){
  return (float)__builtin_bit_cast(_Float16, u);
}
static __device__ __forceinline__ unsigned short f2bf_u(float f){
  __hip_bfloat16 b = __float2bfloat16(f);
  return __builtin_bit_cast(unsigned short, b);
}
static __device__ __forceinline__ float sigmoid_f(float x){
  return 1.0f / (1.0f + __expf(-x));
}
static __device__ __forceinline__ float tanh_f(float x){
  float ax = fabsf(x);
  float e  = __expf(2.0f*ax);          // overflow -> inf is fine: r -> 1
  float r  = 1.0f - 2.0f/(e + 1.0f);
  return copysignf(r, x);
}
static __device__ __forceinline__ f32x4 mfma16x16x32_f16(f16x8 a, f16x8 b, f32x4 c){
  return __builtin_amdgcn_mfma_f32_16x16x32_f16(a, b, c, 0, 0, 0);
}

// ---- converts -------------------------------------------------------------
__global__ __launch_bounds__(256) void cvt_x_kernel(const float* __restrict__ x,
                                                    unsigned short* __restrict__ xh){
  int gid = blockIdx.x*256 + threadIdx.x;          // 2,097,152 threads, 4 elems each
  const float4* xv = (const float4*)x;
  float4 v = xv[gid];
  unsigned int u0 = (unsigned int)f2bf_u(v.x) | ((unsigned int)f2bf_u(v.y) << 16);
  unsigned int u1 = (unsigned int)f2bf_u(v.z) | ((unsigned int)f2bf_u(v.w) << 16);
  ((uint2*)xh)[gid] = make_uint2(u0, u1);
}

// W [256][1024] f32 -> W^T bf16 [dir][1024][256]
__global__ __launch_bounds__(256) void cvt_wt_kernel(const float* __restrict__ Wf,
                                                     const float* __restrict__ Wb,
                                                     unsigned short* __restrict__ wt){
  int gid = blockIdx.x*256 + threadIdx.x;          // 2*1024*256 = 524288
  int d   = gid >> 18;
  int rem = gid & 262143;
  int n   = rem >> 8;
  int k   = rem & 255;
  const float* src = d ? Wb : Wf;
  wt[gid] = f2bf_u(src[k*GG + n]);
}

// R [256][1024] f32 -> R^T f16 [dir][1024 col][256 k]
__global__ __launch_bounds__(256) void cvt_rt_kernel(const float* __restrict__ Rf,
                                                     const float* __restrict__ Rb,
                                                     unsigned short* __restrict__ rt){
  int gid = blockIdx.x*256 + threadIdx.x;          // 2*1024*64 = 131072
  int d   = gid >> 16;
  int rem = gid & 65535;
  int col = rem >> 6;
  int k4  = (rem & 63) << 2;
  const float* src = d ? Rb : Rf;
  unsigned int u0 = (unsigned int)f2h_u(src[(k4+0)*GG + col]) |
                    ((unsigned int)f2h_u(src[(k4+1)*GG + col]) << 16);
  unsigned int u1 = (unsigned int)f2h_u(src[(k4+2)*GG + col]) |
                    ((unsigned int)f2h_u(src[(k4+3)*GG + col]) << 16);
  *(uint2*)(rt + ((size_t)d*1024 + col)*256 + k4) = make_uint2(u0, u1);
}

// ---- proj GEMM: M-tile = 16 batches x 8 timesteps; writes projT[t][col][16b]
__global__ __launch_bounds__(256) void gemm_projT(const unsigned short* __restrict__ Ah,  // xh bf16 [16][2048][256]
                                                  const unsigned short* __restrict__ BTh, // wt bf16 [1024][256], one dir
                                                  unsigned short* __restrict__ Cd,        // projT one dir [Tc][1024][16] f16
                                                  int xstart, int Tc){
  __shared__ __align__(16) unsigned short smem[18432];  // 36864 B
  unsigned short* sA = smem;             // [128][72]
  unsigned short* sB = smem + 9216;      // [128][72]
  unsigned short* sC = smem;             // [128][136] (reuses sA/sB)

  int mt  = blockIdx.x >> 3;             // time-tile (8 t per tile)
  int nt  = blockIdx.x & 7;              // col-tile (128 cols)
  int tid = threadIdx.x;

  const unsigned short* Bb = BTh + (size_t)nt*128*DD;

  int w = tid >> 6, lane = tid & 63, l15 = lane & 15, l4 = lane >> 4;
  int wm = w >> 1, wn = w & 1;

  f32x4 zero4 = {0.0f, 0.0f, 0.0f, 0.0f};
  f32x4 acc[4][4];
#pragma unroll
  for (int i = 0; i < 4; ++i)
#pragma unroll
    for (int j = 0; j < 4; ++j) acc[i][j] = zero4;

  for (int kt = 0; kt < 4; ++kt){
    __syncthreads();
#pragma unroll
    for (int i = 0; i < 4; ++i){
      int ch = tid + i*256;
      int r = ch >> 3, c8 = ch & 7;
      int bb = r >> 3, ti = r & 7;
      int tx = xstart + mt*8 + ti;       // both dirs: ascending x-rows from xstart
      *(uint4*)(sA + r*72 + c8*8) = *(const uint4*)(Ah + ((size_t)bb*TT + tx)*DD + kt*64 + c8*8);
      *(uint4*)(sB + r*72 + c8*8) = *(const uint4*)(Bb + (size_t)r*DD + kt*64 + c8*8);
    }
    __syncthreads();
#pragma unroll
    for (int ks = 0; ks < 2; ++ks){
      short8 a[4], b[4];
#pragma unroll
      for (int mf = 0; mf < 4; ++mf)
        a[mf] = *(const short8*)(sA + (wm*64 + mf*16 + l15)*72 + ks*32 + l4*8);
#pragma unroll
      for (int nf = 0; nf < 4; ++nf)
        b[nf] = *(const short8*)(sB + (wn*64 + nf*16 + l15)*72 + ks*32 + l4*8);
#pragma unroll
      for (int mf = 0; mf < 4; ++mf)
#pragma unroll
        for (int nf = 0; nf < 4; ++nf)
          acc[mf][nf] = __builtin_amdgcn_mfma_f32_16x16x32_bf16(a[mf], b[nf], acc[mf][nf], 0, 0, 0);
    }
  }
  __syncthreads();
#pragma unroll
  for (int mf = 0; mf < 4; ++mf)
#pragma unroll
    for (int nf = 0; nf < 4; ++nf)
#pragma unroll
      for (int r = 0; r < 4; ++r)
        sC[(wm*64 + mf*16 + l4*4 + r)*136 + wn*64 + nf*16 + l15] = f2h_u(acc[mf][nf][r]);
  __syncthreads();
  // write 8 time-slabs: projT[row][col][b], 4 KB contiguous each
  int c = tid >> 1, half = tid & 1;      // c 0..127, half 0..1 (b 0..7 / 8..15)
#pragma unroll
  for (int ti = 0; ti < 8; ++ti){
    unsigned short* slab = Cd + ((size_t)(mt*8 + ti)*GG + nt*128)*16;
    unsigned short v[8];
#pragma unroll
    for (int j = 0; j < 8; ++j)
      v[j] = sC[((half*8 + j)*8 + ti)*136 + c];
    uint4 pk;
    pk.x = (unsigned int)v[0] | ((unsigned int)v[1] << 16);
    pk.y = (unsigned int)v[2] | ((unsigned int)v[3] << 16);
    pk.z = (unsigned int)v[4] | ((unsigned int)v[5] << 16);
    pk.w = (unsigned int)v[6] | ((unsigned int)v[7] << 16);
    *(uint4*)(slab + c*16 + half*8) = pk;
  }
}

// ---- MFMA LSTM scan: 2 blocks per direction, pairwise h-exchange ----------
template<int P>
__device__ __forceinline__ void scan_body(
    unsigned short (*h_lds)[264],
    const unsigned short* __restrict__ projT,  // [2][Tc][1024][16] f16
    const unsigned short* __restrict__ Rt,     // [2][1024][256] f16
    const float* __restrict__ bcf, const float* __restrict__ bcb,
    float* __restrict__ out,
    float* __restrict__ stH, float* __restrict__ stC,
    unsigned long long* __restrict__ xchg,     // [2][2][256][4] ull
    int* __restrict__ flags,                   // [4][16] int
    int t0, int t1, int Tc, int first, int d)
{
  int tid = threadIdx.x;
  int w = tid >> 6, l = tid & 63, l15 = l & 15, l4 = l >> 4;
  int u0 = P*128 + w*16;                 // wave's global unit base
  int b4 = l4*4;

  // ---- register-resident B-fragments of R: rf[gate][ks], 128 VGPRs ----
  f16x8 rf[4][8];
  {
    const unsigned short* Rd = Rt + (size_t)d*1024*256;
#pragma unroll
    for (int g = 0; g < 4; ++g){
      const unsigned short* colp = Rd + (size_t)(g*256 + u0 + l15)*256 + l4*8;
#pragma unroll
      for (int ks = 0; ks < 8; ++ks)
        rf[g][ks] = *(const f16x8*)(colp + ks*32);
    }
  }

  // ---- init h_lds (full h: both halves) + c-state ----
  const float* stHb = stH + d*16*256;
  for (int idx = tid; idx < 16*264; idx += 512){
    int bb = idx / 264, cc = idx - bb*264;
    unsigned short v = 0;
    if (cc < 256 && !first) v = f2h_u(stHb[bb*256 + cc]);
    h_lds[bb][cc] = v;
  }
  f32x4 cst = {0.f,0.f,0.f,0.f};
  if (!first){
#pragma unroll
    for (int r = 0; r < 4; ++r)
      cst[r] = stC[((size_t)d*16 + b4 + r)*256 + u0 + l15];
  }
  float bc_r = (d ? bcb : bcf)[u0 + l15];

  const int me = d*2 + P, pa = d*2 + (1-P);
  constexpr int OWN_KS = P*4;            // own K-steps (own unit half feeds these k)
  constexpr int PAR_KS = 4 - P*4;
  constexpr int PAR_UB = (1-P)*128;

  // loop-invariant address pieces
  const unsigned short* prj = projT + (size_t)d*Tc*16384;
  int poff[4];
#pragma unroll
  for (int g = 0; g < 4; ++g) poff[g] = (g*256 + u0 + l15)*16 + b4;
  float* outb = out + (size_t)b4*TT*512 + d*256 + u0 + l15;
  size_t xw_base = ((size_t)d*2)*1024 + (u0 + l15)*4 + l4;          // + (s&1)*1024
  size_t xi_base = ((size_t)d*2)*1024 + (PAR_UB + (tid >> 2))*4 + (tid & 3);
  int imp_row = (tid & 3)*4, imp_col = PAR_UB + (tid >> 2);

  const int Tl = t1 - t0;
  float hh[4] = {0.f,0.f,0.f,0.f};

  __syncthreads();

  for (int s = 0; s < Tl; ++s){
    int t = t0 + s;
    int ps = d ? (Tl - 1 - s) : s;
    // issue proj loads first (latency hides under phase A + spin)
    const unsigned short* pr = prj + (size_t)ps*16384;
    uint2 pj0 = *(const uint2*)(pr + poff[0]);
    uint2 pj1 = *(const uint2*)(pr + poff[1]);
    uint2 pj2 = *(const uint2*)(pr + poff[2]);
    uint2 pj3 = *(const uint2*)(pr + poff[3]);

    f32x4 acc0 = {0.f,0.f,0.f,0.f}, acc1 = acc0, acc2 = acc0, acc3 = acc0;
    // ---- phase A: own-half K (h written by this block last step) ----
#pragma unroll
    for (int ks = 0; ks < 4; ++ks){
      f16x8 af = *(const f16x8*)&h_lds[l15][(OWN_KS + ks)*32 + l4*8];
      acc0 = mfma16x16x32_f16(af, rf[0][OWN_KS + ks], acc0);
      acc1 = mfma16x16x32_f16(af, rf[1][OWN_KS + ks], acc1);
      acc2 = mfma16x16x32_f16(af, rf[2][OWN_KS + ks], acc2);
      acc3 = mfma16x16x32_f16(af, rf[3][OWN_KS + ks], acc3);
    }
    // ---- import partner half (h of step s-1) ----
    if (s > 0){
      while (__hip_atomic_load(&flags[pa*16], __ATOMIC_ACQUIRE, __HIP_MEMORY_SCOPE_AGENT) < s)
        __builtin_amdgcn_s_sleep(1);
      unsigned long long v = __hip_atomic_load(&xchg[xi_base + (size_t)((s-1)&1)*1024],
                                               __ATOMIC_RELAXED, __HIP_MEMORY_SCOPE_AGENT);
#pragma unroll
      for (int rr = 0; rr < 4; ++rr)
        h_lds[imp_row + rr][imp_col] = (unsigned short)(v >> (16*rr));
    }
    __syncthreads();
    // ---- phase B: partner-half K ----
#pragma unroll
    for (int ks = 0; ks < 4; ++ks){
      f16x8 af = *(const f16x8*)&h_lds[l15][(PAR_KS + ks)*32 + l4*8];
      acc0 = mfma16x16x32_f16(af, rf[0][PAR_KS + ks], acc0);
      acc1 = mfma16x16x32_f16(af, rf[1][PAR_KS + ks], acc1);
      acc2 = mfma16x16x32_f16(af, rf[2][PAR_KS + ks], acc2);
      acc3 = mfma16x16x32_f16(af, rf[3][PAR_KS + ks], acc3);
    }
    // ---- epilogue: gates + state update (4 batches per lane) ----
    float pjf0[4], pjf1[4], pjf2[4], pjf3[4];
    pjf0[0]=h2f((unsigned short)pj0.x); pjf0[1]=h2f((unsigned short)(pj0.x>>16));
    pjf0[2]=h2f((unsigned short)pj0.y); pjf0[3]=h2f((unsigned short)(pj0.y>>16));
    pjf1[0]=h2f((unsigned short)pj1.x); pjf1[1]=h2f((unsigned short)(pj1.x>>16));
    pjf1[2]=h2f((unsigned short)pj1.y); pjf1[3]=h2f((unsigned short)(pj1.y>>16));
    pjf2[0]=h2f((unsigned short)pj2.x); pjf2[1]=h2f((unsigned short)(pj2.x>>16));
    pjf2[2]=h2f((unsigned short)pj2.y); pjf2[3]=h2f((unsigned short)(pj2.y>>16));
    pjf3[0]=h2f((unsigned short)pj3.x); pjf3[1]=h2f((unsigned short)(pj3.x>>16));
    pjf3[2]=h2f((unsigned short)pj3.y); pjf3[3]=h2f((unsigned short)(pj3.y>>16));
    unsigned long long xv = 0;
#pragma unroll
    for (int r = 0; r < 4; ++r){
      float gi = acc0[r] + pjf0[r];
      float gf = acc1[r] + pjf1[r];
      float go = acc2[r] + pjf2[r];
      float gc = acc3[r] + pjf3[r] + bc_r;
      float ig = sigmoid_f(gi);
      float fg = sigmoid_f(gf);
      float og = sigmoid_f(go);
      float cand = tanh_f(gc);
      cst[r] = sigmoid_f(fg*cst[r] + ig*cand);     // faithful quirk
      float h = tanh_f(cst[r]) * og;               // faithful quirk
      outb[((size_t)r*TT + t)*512] = h;
      hh[r] = h;
      unsigned short hu = f2h_u(h);
      h_lds[b4 + r][u0 + l15] = hu;                // own half (disjoint from phase-B reads)
      xv |= (unsigned long long)hu << (16*r);
    }
    __hip_atomic_store(&xchg[xw_base + (size_t)(s&1)*1024], xv,
                       __ATOMIC_RELAXED, __HIP_MEMORY_SCOPE_AGENT);
    __syncthreads();                                // all h_lds writes + xchg stores drained
    if (tid == 0)
      __hip_atomic_store(&flags[me*16], s+1, __ATOMIC_RELEASE, __HIP_MEMORY_SCOPE_AGENT);
  }

  // chunk-carry state
#pragma unroll
  for (int r = 0; r < 4; ++r){
    stC[((size_t)d*16 + b4 + r)*256 + u0 + l15] = cst[r];
    stH[((size_t)d*16 + b4 + r)*256 + u0 + l15] = hh[r];
  }
}

__global__ __launch_bounds__(512) __attribute__((amdgpu_waves_per_eu(2, 2)))
void lstm_scan_mfma(const unsigned short* __restrict__ projT,
                    const unsigned short* __restrict__ Rt,
                    const float* __restrict__ bcf, const float* __restrict__ bcb,
                    float* __restrict__ out,
                    float* __restrict__ stH, float* __restrict__ stC,
                    unsigned long long* __restrict__ xchg,
                    int* __restrict__ flags,
                    int t0, int t1, int Tc, int first)
{
  __shared__ __align__(16) unsigned short h_lds[16][264];
  int blk = blockIdx.x;
  int d = blk & 7, p = blk >> 3;
  if (d >= 2) return;
  if (p == 0) scan_body<0>(h_lds, projT, Rt, bcf, bcb, out, stH, stC, xchg, flags, t0, t1, Tc, first, d);
  else        scan_body<1>(h_lds, projT, Rt, bcf, bcb, out, stH, stC, xchg, flags, t0, t1, Tc, first, d);
}

// ---- launcher -------------------------------------------------------------
extern "C" void kernel_launch(void* const* d_in, const int* in_sizes, int n_in,
                              void* d_out, int out_size, void* d_ws, size_t ws_size,
                              hipStream_t stream){
  const float* x   = (const float*)d_in[0];
  const float* Wf  = (const float*)d_in[1];
  const float* Rf  = (const float*)d_in[2];
  const float* bcf = (const float*)d_in[3];
  const float* Wb  = (const float*)d_in[4];
  const float* Rb  = (const float*)d_in[5];
  const float* bcb = (const float*)d_in[6];
  float* out = (float*)d_out;
  char* ws = (char*)d_ws;

  const size_t OFF_XH    = 0;                        // 16 MiB: x bf16
  const size_t OFF_WT    = 16777216;                 // 1 MiB: W^T bf16 both dirs
  const size_t OFF_RT    = OFF_WT + 1048576;         // 1 MiB: R^T f16 both dirs
  const size_t OFF_STH   = OFF_RT + 1048576;         // 32 KiB h state
  const size_t OFF_STC   = OFF_STH + 32768;          // 32 KiB c state
  const size_t OFF_XCHG  = OFF_STC + 32768;          // 32 KiB h exchange
  const size_t OFF_FLAGS = OFF_XCHG + 32768;         // 4 KiB flags
  const size_t OFF_PROJT = OFF_FLAGS + 4096;         // projT chunk buffer

  unsigned short* xh    = (unsigned short*)(ws + OFF_XH);
  unsigned short* wt    = (unsigned short*)(ws + OFF_WT);
  unsigned short* rt    = (unsigned short*)(ws + OFF_RT);
  float*          stH   = (float*)(ws + OFF_STH);
  float*          stC   = (float*)(ws + OFF_STC);
  unsigned long long* xchg = (unsigned long long*)(ws + OFF_XCHG);
  int*            flags = (int*)(ws + OFF_FLAGS);
  unsigned short* projT = (unsigned short*)(ws + OFF_PROJT);

  int Tc = TT;  // time-chunk; shrink if ws too small (projT = 65536*Tc bytes)
  while (Tc > 128 && OFF_PROJT + (size_t)65536*Tc > ws_size) Tc >>= 1;

  cvt_x_kernel<<<8192, 256, 0, stream>>>(x, xh);
  cvt_wt_kernel<<<2048, 256, 0, stream>>>(Wf, Wb, wt);
  cvt_rt_kernel<<<512, 256, 0, stream>>>(Rf, Rb, rt);

  int nch = TT / Tc;
  for (int ch = 0; ch < nch; ++ch){
    int t0 = ch*Tc, t1 = t0 + Tc;
    gemm_projT<<<Tc, 256, 0, stream>>>(xh, wt,          projT,                     t0,      Tc);
    gemm_projT<<<Tc, 256, 0, stream>>>(xh, wt + 262144, projT + (size_t)Tc*GG*16,  TT - t1, Tc);
    hipMemsetAsync(flags, 0, 256, stream);
    lstm_scan_mfma<<<16, 512, 0, stream>>>(projT, rt, bcf, bcb, out, stH, stC, xchg, flags,
                                           t0, t1, Tc, ch == 0 ? 1 : 0);
  }
}